// Round 1
// baseline (110.282 us; speedup 1.0000x reference)
//
#include <hip/hip_runtime.h>

// NCC (local normalized cross-correlation) loss, win=9^3, SAME zero padding.
// Volume: (B=2, C=1, D=160, H=192, W=160) fp32. Output: scalar fp32 loss.
//
// Fused single-pass design:
//  - block = 256 threads, output tile 16x16 (x,y), streams along z in chunks of 32
//  - each thread owns 2-3 input halo columns (24x24=576), keeps ring[I,J][9] in
//    registers and 5 incremental running z-box-sums per column
//  - per z-step: write 5 z-summed slices to LDS, x-boxsum via register sliding
//    window (float4 LDS reads), y-boxsum via 9 taps (2-way bank alias = free),
//    then cc and per-thread accumulation
//  - deterministic two-stage reduction through d_ws (no fp32 atomics)

#define NX 160
#define NY 192
#define NZ 160
#define NB 2
#define SLICE (NX * NY)          // 30720
#define VOL   (SLICE * NZ)       // 4915200
#define TOTAL (VOL * NB)         // 9830400

#define TX 16
#define TY 16
#define ZC 32
#define GX (NX / TX)             // 10
#define GY (NY / TY)             // 12
#define GZ (NZ / ZC)             // 5
#define NPART (GX * GY * GZ * NB) // 1200

#define HALO 24                  // TX + 8
#define NCOL (HALO * HALO)       // 576
#define INV729 (1.0f / 729.0f)

static_assert(NCOL - 512 == 64, "third-column ownership assumes 64 extra columns");

__global__ __launch_bounds__(256) void ncc_main(
    const float* __restrict__ J_pred,   // predict
    const float* __restrict__ I_targ,   // target
    float* __restrict__ partial)
{
    const int tid = threadIdx.x;
    const int x0 = blockIdx.x * TX;
    const int y0 = blockIdx.y * TY;
    const int b  = blockIdx.z / GZ;
    const int z0 = (blockIdx.z % GZ) * ZC;

    __shared__ __align__(16) float Zq[5][NCOL];       // z-boxsummed slices (11.5 KB)
    __shared__ __align__(16) float Rq[5][HALO][TX];   // x-boxsummed rows   (7.7 KB)
    __shared__ float redbuf[4];

    // ---- column ownership: c = tid, tid+256, tid+512 (<576) ----
    int  cbase[3];
    bool cexist[3], cvalid[3];
#pragma unroll
    for (int ci = 0; ci < 3; ++ci) {
        int c  = tid + ci * 256;
        int r  = c / HALO;
        int xc = c - r * HALO;
        int gy = y0 - 4 + r;
        int gx = x0 - 4 + xc;
        cexist[ci] = (c < NCOL);
        cvalid[ci] = cexist[ci] && ((unsigned)gy < (unsigned)NY) && ((unsigned)gx < (unsigned)NX);
        cbase[ci]  = cvalid[ci] ? (gy * NX + gx) : 0;
    }
    const size_t bvol = (size_t)b * VOL;

    // ---- per-column z-ring state (registers, all statically indexed) ----
    float ringI[3][9], ringJ[3][9], run[3][5];
#pragma unroll
    for (int ci = 0; ci < 3; ++ci) {
#pragma unroll
        for (int k = 0; k < 9; ++k) { ringI[ci][k] = 0.f; ringJ[ci][k] = 0.f; }
#pragma unroll
        for (int q = 0; q < 5; ++q) run[ci][q] = 0.f;
    }

    auto update = [&](int zin) {
        const bool zok = ((unsigned)zin < (unsigned)NZ);
        const size_t zoff = bvol + (size_t)zin * SLICE;
#pragma unroll
        for (int ci = 0; ci < 3; ++ci) {
            float iN = 0.f, jN = 0.f;
            if (zok && cvalid[ci]) {
                size_t off = zoff + (size_t)cbase[ci];
                iN = I_targ[off];
                jN = J_pred[off];
            }
            float i0 = ringI[ci][0], j0 = ringJ[ci][0];
            run[ci][0] += iN - i0;
            run[ci][1] += jN - j0;
            run[ci][2] += iN * iN - i0 * i0;
            run[ci][3] += jN * jN - j0 * j0;
            run[ci][4] += iN * jN - i0 * j0;
#pragma unroll
            for (int k = 0; k < 8; ++k) {
                ringI[ci][k] = ringI[ci][k + 1];
                ringJ[ci][k] = ringJ[ci][k + 1];
            }
            ringI[ci][8] = iN;
            ringJ[ci][8] = jN;
        }
    };

    // ---- warm up ring with slices z0-4 .. z0+3 (zero-padded at volume edges) ----
#pragma unroll 1
    for (int s = 0; s < 8; ++s) update(z0 - 4 + s);

    const int ty = tid >> 4, tx = tid & 15;
    float acc = 0.f;

#pragma unroll 1
    for (int so = 0; so < ZC; ++so) {
        update(z0 + 4 + so);   // run[] now holds z-boxsum centered at z0+so

        // stage z-summed slices
#pragma unroll
        for (int ci = 0; ci < 3; ++ci) {
            int c = tid + ci * 256;
            if (cexist[ci]) {
#pragma unroll
                for (int q = 0; q < 5; ++q) Zq[q][c] = run[ci][q];
            }
        }
        __syncthreads();

        // x-boxsum: 240 tasks = 24 rows x 5 quantities x 2 halves, sliding window
        if (tid < 240) {
            int q   = tid / 48;
            int rem = tid - q * 48;
            int row = rem >> 1;
            int h   = rem & 1;
            const float* src = &Zq[q][row * HALO + h * 8];
            float4 v0 = *(const float4*)(src + 0);
            float4 v1 = *(const float4*)(src + 4);
            float4 v2 = *(const float4*)(src + 8);
            float4 v3 = *(const float4*)(src + 12);
            float c_[16] = { v0.x, v0.y, v0.z, v0.w, v1.x, v1.y, v1.z, v1.w,
                             v2.x, v2.y, v2.z, v2.w, v3.x, v3.y, v3.z, v3.w };
            float s = c_[0] + c_[1] + c_[2] + c_[3] + c_[4]
                    + c_[5] + c_[6] + c_[7] + c_[8];
            float o[8];
            o[0] = s;
#pragma unroll
            for (int i = 1; i < 8; ++i) { s += c_[i + 8] - c_[i - 1]; o[i] = s; }
            float4 w0 = { o[0], o[1], o[2], o[3] };
            float4 w1 = { o[4], o[5], o[6], o[7] };
            *(float4*)(&Rq[q][row][h * 8 + 0]) = w0;
            *(float4*)(&Rq[q][row][h * 8 + 4]) = w1;
        }
        __syncthreads();

        // y-boxsum (9 taps, 2-way bank alias = free) + cc
        float S0 = 0.f, S1 = 0.f, S2 = 0.f, S3 = 0.f, S4 = 0.f;
#pragma unroll
        for (int k = 0; k < 9; ++k) {
            S0 += Rq[0][ty + k][tx];
            S1 += Rq[1][ty + k][tx];
            S2 += Rq[2][ty + k][tx];
            S3 += Rq[3][ty + k][tx];
            S4 += Rq[4][ty + k][tx];
        }
        float cross = S4 - S0 * S1 * INV729;
        float Iv    = S2 - S0 * S0 * INV729;
        float Jv    = S3 - S1 * S1 * INV729;
        float cc    = (cross * cross) / (Iv * Jv + 1e-5f);
        acc += cc;
    }

    // ---- block reduction (deterministic within block) ----
#pragma unroll
    for (int off = 32; off > 0; off >>= 1) acc += __shfl_down(acc, off);
    if ((tid & 63) == 0) redbuf[tid >> 6] = acc;
    __syncthreads();
    if (tid == 0) {
        int bid = blockIdx.x + GX * (blockIdx.y + GY * blockIdx.z);
        partial[bid] = redbuf[0] + redbuf[1] + redbuf[2] + redbuf[3];
    }
}

__global__ __launch_bounds__(256) void ncc_final(
    const float* __restrict__ partial, float* __restrict__ out)
{
    __shared__ float sm[256];
    const int tid = threadIdx.x;
    float s = 0.f;
    for (int i = tid; i < NPART; i += 256) s += partial[i];
    sm[tid] = s;
    __syncthreads();
#pragma unroll
    for (int w = 128; w > 0; w >>= 1) {
        if (tid < w) sm[tid] += sm[tid + w];
        __syncthreads();
    }
    if (tid == 0) out[0] = 1.0f - sm[0] * (1.0f / (float)TOTAL);
}

extern "C" void kernel_launch(void* const* d_in, const int* in_sizes, int n_in,
                              void* d_out, int out_size, void* d_ws, size_t ws_size,
                              hipStream_t stream)
{
    const float* predict = (const float*)d_in[0];  // J
    const float* target  = (const float*)d_in[1];  // I
    float* partial = (float*)d_ws;                 // 1200 floats (4.8 KB)

    dim3 grid(GX, GY, GZ * NB);
    ncc_main<<<grid, 256, 0, stream>>>(predict, target, partial);
    ncc_final<<<1, 256, 0, stream>>>(partial, (float*)d_out);
}